// Round 18
// baseline (336.710 us; speedup 1.0000x reference)
//
#include <hip/hip_runtime.h>
#include <math.h>

namespace {
constexpr int B_   = 64;
constexpr int NPG  = 2048;
constexpr int N0   = B_ * NPG;      // 131072
constexpr int E0   = N0 * 4;        // 524288
constexpr int H_   = 128;
constexpr int K1   = 1639, K2 = 1312, K3 = 1050;
constexpr int N1   = B_ * K1;       // 104896
constexpr int N2   = B_ * K2;       // 83968
constexpr int N3   = B_ * K3;       // 67200
constexpr int ACT  = 124;
constexpr int RS   = 32;            // readout segments (level 3)
constexpr int Gm1  = (K1 + 63) / 64;   // 26 mmh blocks/graph, level 1
constexpr int Gm2  = (K2 + 63) / 64;   // 21 mmh blocks/graph, level 2
}

typedef short bf16x8 __attribute__((ext_vector_type(8)));
typedef float f32x4  __attribute__((ext_vector_type(4)));

__device__ __forceinline__ unsigned short f2bf(float f)
{
    unsigned x = __float_as_uint(f);
    x = x + 0x7FFFu + ((x >> 16) & 1u);    // round-to-nearest-even
    return (unsigned short)(x >> 16);
}

// ---------- pack W2+W3 (128x128 f32 [k][n]) -> WT2,WT3 bf16 [n][k] ----------
__global__ void pack_k(const float* __restrict__ W2, unsigned short* __restrict__ WT2,
                       const float* __restrict__ W3, unsigned short* __restrict__ WT3)
{
    int t = blockIdx.x * 256 + threadIdx.x;   // 32768 threads
    int which = t >> 14;
    int i = t & 16383;
    int n = i >> 7, k = i & 127;
    if (which == 0) WT2[n * 128 + k] = f2bf(W2[k * 128 + n]);
    else            WT3[n * 128 + k] = f2bf(W3[k * 128 + n]);
}

// ---------- h[g,j,:] = (Xin[selOld[g*K+j],:]*score) @ W via bf16 MFMA ----------
// (unchanged from r17: XCD-swizzled per-graph blocks, in-wave readout fold)
__global__ __launch_bounds__(256) void mmh_k(const float* __restrict__ Xin,
                                             const int* __restrict__ selOld,
                                             const float* __restrict__ score,
                                             const unsigned short* __restrict__ WT,
                                             float* __restrict__ C,
                                             float* __restrict__ part,
                                             int K, int Gm)
{
    __shared__ unsigned short sA[64 * 128];   // 16 KB
    char* sAb = (char*)sA;
    int tid = threadIdx.x;
    int pb  = blockIdx.x;
    int x8  = pb & 7;
    int m   = pb >> 3;
    int g   = x8 + 8 * (m / Gm);
    int lb  = m % Gm;
    int jbase = lb * 64;
    const int* selg = selOld + (size_t)g * K;
    int rr = tid & 7;                 // row offset within 8-row stripe (in-wave group)
    int cc = (tid >> 3) * 4;          // this thread's 4 cols

    int   selv[8];
    float scv[8];
    #pragma unroll
    for (int ch = 0; ch < 8; ++ch) {
        int j = jbase + ch * 8 + rr;
        selv[ch] = (j < K) ? selg[j] : -1;
    }
    #pragma unroll
    for (int ch = 0; ch < 8; ++ch)
        scv[ch] = (selv[ch] >= 0) ? score[selv[ch]] : 0.f;

    float4 pmax = make_float4(-3.4e38f, -3.4e38f, -3.4e38f, -3.4e38f);
    float4 psum = make_float4(0.f, 0.f, 0.f, 0.f);
    #pragma unroll
    for (int ch = 0; ch < 8; ++ch) {
        int r = ch * 8 + rr;
        unsigned int lo = 0u, hi = 0u;
        if (selv[ch] >= 0) {
            float sc = scv[ch];
            float4 v = *(const float4*)(Xin + (size_t)selv[ch] * H_ + cc);
            v.x *= sc; v.y *= sc; v.z *= sc; v.w *= sc;
            pmax.x = fmaxf(pmax.x, v.x); pmax.y = fmaxf(pmax.y, v.y);
            pmax.z = fmaxf(pmax.z, v.z); pmax.w = fmaxf(pmax.w, v.w);
            psum.x += v.x; psum.y += v.y; psum.z += v.z; psum.w += v.w;
            unsigned short h0 = f2bf(v.x), h1 = f2bf(v.y);
            unsigned short h2 = f2bf(v.z), h3 = f2bf(v.w);
            lo = (unsigned int)h0 | ((unsigned int)h1 << 16);
            hi = (unsigned int)h2 | ((unsigned int)h3 << 16);
        }
        int off = (r * 256 + cc * 2) ^ ((r & 7) << 4);
        *(unsigned int*)(sAb + off)     = lo;
        *(unsigned int*)(sAb + off + 4) = hi;
    }
    #pragma unroll
    for (int d = 1; d < 8; d <<= 1) {
        pmax.x = fmaxf(pmax.x, __shfl_xor(pmax.x, d));
        pmax.y = fmaxf(pmax.y, __shfl_xor(pmax.y, d));
        pmax.z = fmaxf(pmax.z, __shfl_xor(pmax.z, d));
        pmax.w = fmaxf(pmax.w, __shfl_xor(pmax.w, d));
        psum.x += __shfl_xor(psum.x, d);
        psum.y += __shfl_xor(psum.y, d);
        psum.z += __shfl_xor(psum.z, d);
        psum.w += __shfl_xor(psum.w, d);
    }
    if (rr == 0) {
        float* pr = part + ((size_t)g * Gm + lb) * 256;
        *(float4*)(pr + cc)       = pmax;
        *(float4*)(pr + 128 + cc) = psum;
    }
    __syncthreads();

    int w    = tid >> 6;
    int lane = tid & 63;
    int l16  = lane & 15;
    int lq   = lane >> 4;
    int arow = w * 16 + l16;

    f32x4 acc[8];
    #pragma unroll
    for (int ct = 0; ct < 8; ++ct) acc[ct] = (f32x4){0.f, 0.f, 0.f, 0.f};

    #pragma unroll
    for (int ks = 0; ks < 4; ++ks) {
        int aoff = (arow * 256 + ks * 64 + lq * 16) ^ ((arow & 7) << 4);
        bf16x8 af = *(const bf16x8*)(sAb + aoff);
        #pragma unroll
        for (int ct = 0; ct < 8; ++ct) {
            const unsigned short* bp = WT + (ct * 16 + l16) * 128 + ks * 32 + lq * 8;
            bf16x8 bf = *(const bf16x8*)bp;
            acc[ct] = __builtin_amdgcn_mfma_f32_16x16x32_bf16(af, bf, acc[ct], 0, 0, 0);
        }
    }
    int jb = jbase + w * 16 + lq * 4;
    #pragma unroll
    for (int ct = 0; ct < 8; ++ct) {
        int col = ct * 16 + l16;
        float* cp = C + ((size_t)g * K + jb) * H_ + col;
        if (jb + 0 < K) cp[0 * H_] = acc[ct][0];
        if (jb + 1 < K) cp[1 * H_] = acc[ct][1];
        if (jb + 2 < K) cp[2 * H_] = acc[ct][2];
        if (jb + 3 < K) cp[3 * H_] = acc[ct][3];
    }
}

// ---------- degree count (level 0 only) ----------
__global__ void count_deg_k(const int* __restrict__ dst, int E, int* __restrict__ deg)
{
    int e = blockIdx.x * blockDim.x + threadIdx.x;
    if (e < E) atomicAdd(deg + dst[e], 1);
}

// ---------- exclusive scan over deg[0..n-1] (level 0) ----------
__global__ __launch_bounds__(1024) void scan1_k(const int* __restrict__ in, int* __restrict__ out,
                                                int* __restrict__ bsum, int n)
{
    __shared__ int s[1024];
    int t = threadIdx.x;
    int i = blockIdx.x * 1024 + t;
    int v = (i < n) ? in[i] : 0;
    s[t] = v;
    __syncthreads();
    for (int d = 1; d < 1024; d <<= 1) {
        int add = (t >= d) ? s[t - d] : 0;
        __syncthreads();
        s[t] += add;
        __syncthreads();
    }
    if (i < n) out[i] = s[t] - v;
    if (t == 1023) bsum[blockIdx.x] = s[1023];
}

// ---------- scan with inline degree computation from prev-level CSR (int2 edges) ----------
__global__ __launch_bounds__(1024) void scan1b_k(const int* __restrict__ selOld,
                                                 const int* __restrict__ proff,
                                                 const int2* __restrict__ pcs,
                                                 const int* __restrict__ newpos,
                                                 int* __restrict__ deg,
                                                 int* __restrict__ out,
                                                 int* __restrict__ bsum, int n)
{
    __shared__ int s[1024];
    int t = threadIdx.x;
    int i = blockIdx.x * 1024 + t;
    int v = 0;
    if (i < n - 1) {
        int o = selOld[i];
        int e1 = proff[o + 1];
        for (int e = proff[o]; e < e1; ++e) v += (newpos[pcs[e].x] >= 0) ? 1 : 0;
    }
    if (i < n) deg[i] = v;
    s[t] = v;
    __syncthreads();
    for (int d = 1; d < 1024; d <<= 1) {
        int add = (t >= d) ? s[t - d] : 0;
        __syncthreads();
        s[t] += add;
        __syncthreads();
    }
    if (i < n) out[i] = s[t] - v;
    if (t == 1023) bsum[blockIdx.x] = s[1023];
}

// parallel block-sum scan (nb <= 256) + parallel 1/||p||
__global__ __launch_bounds__(256) void scan2_k(int* __restrict__ bsum, int nb,
                                               const float* __restrict__ p,
                                               float* __restrict__ invnOut)
{
    __shared__ int s[256];
    __shared__ float ps[128];
    int t = threadIdx.x;
    int v = (t < nb) ? bsum[t] : 0;
    s[t] = v;
    if (p && t < 128) ps[t] = p[t] * p[t];
    __syncthreads();
    for (int d = 1; d < 256; d <<= 1) {
        int add = (t >= d) ? s[t - d] : 0;
        __syncthreads();
        s[t] += add;
        __syncthreads();
    }
    if (t < nb) bsum[t] = s[t] - v;
    for (int d = 64; d > 0; d >>= 1) {
        if (p && t < d) ps[t] += ps[t + d];
        __syncthreads();
    }
    if (p && t == 0) *invnOut = rsqrtf(ps[0]);
}

__global__ void scan3_k(int* __restrict__ out, const int* __restrict__ bsum, int n,
                        const int* __restrict__ deg, float* __restrict__ dis)
{
    int i = blockIdx.x * blockDim.x + threadIdx.x;
    if (i < n) {
        out[i] += bsum[i >> 10];
        dis[i] = rsqrtf((float)deg[i] + 1.0f);
    }
}

// ---------- level-0 counting-sort fill (atomic); edge payload = {src, dis[src]} ----------
__global__ void fill_k(const int* __restrict__ src, const int* __restrict__ dst, int E,
                       const int* __restrict__ rowoff, int* __restrict__ cur,
                       const float* __restrict__ dis, int2* __restrict__ esrc)
{
    int e = blockIdx.x * blockDim.x + threadIdx.x;
    if (e >= E) return;
    int d = dst[e];
    int s = src[e];
    int pos = rowoff[d] + atomicAdd(cur + d, 1);
    esrc[pos] = make_int2(s, __float_as_int(dis[s]));
}

// ---------- levels 1-2 row-based CSR fill; edge payload = {m, dis[m]} ----------
__global__ void fill_row_k(const int* __restrict__ selOld,
                           const int* __restrict__ proff, const int2* __restrict__ pcs,
                           const int* __restrict__ newpos, const int* __restrict__ roff,
                           const float* __restrict__ dis, int2* __restrict__ cs, int nNodes)
{
    int i = blockIdx.x * blockDim.x + threadIdx.x;
    if (i >= nNodes) return;
    int o = selOld[i];
    int wptr = roff[i];
    int e1 = proff[o + 1];
    for (int e = proff[o]; e < e1; ++e) {
        int m = newpos[pcs[e].x];
        if (m >= 0) cs[wptr++] = make_int2(m, __float_as_int(dis[m]));
    }
}

// ---------- level-0 fused GCN, phase-split (int2 edges) ----------
__global__ __launch_bounds__(256) void aggx_k(const float* __restrict__ X,
                                              const int* __restrict__ rowoff,
                                              const int2* __restrict__ esrc,
                                              const float* __restrict__ dis,
                                              const float* __restrict__ W1,
                                              const float* __restrict__ b1,
                                              const float* __restrict__ p1,
                                              const float* __restrict__ invn,
                                              float* __restrict__ out,
                                              float* __restrict__ score,
                                              int npg, int Gb)
{
    __shared__ float sW[512];
    __shared__ float sb[128];
    __shared__ float sp[128];
    __shared__ float sxa[256 * 4];
    __shared__ float sdt[256];
    int tid = threadIdx.x;
    for (int i = tid; i < 512; i += 256) sW[i] = W1[i];
    if (tid < 128) { sb[tid] = b1[tid]; sp[tid] = p1[tid]; }
    int pb = blockIdx.x;
    int x8 = pb & 7;
    int m  = pb >> 3;
    int g  = x8 + 8 * (m / Gb);
    int lb = m % Gb;
    int nbase = g * npg + lb * 256;
    int n = nbase + tid;
    float dn = dis[n];
    float4 xa = *(const float4*)(X + (size_t)n * 4);
    float s2 = dn * dn;
    xa.x *= s2; xa.y *= s2; xa.z *= s2; xa.w *= s2;
    int beg = rowoff[n], end = rowoff[n + 1];
    for (int e = beg; e < end; ++e) {
        int2 ed = esrc[e];
        float c = __int_as_float(ed.y) * dn;
        float4 xs = *(const float4*)(X + (size_t)ed.x * 4);
        xa.x += xs.x * c; xa.y += xs.y * c; xa.z += xs.z * c; xa.w += xs.w * c;
    }
    *(float4*)(sxa + tid * 4) = xa;
    __syncthreads();
    int wv = tid >> 6;
    int lane = tid & 63;
    int c0 = lane * 2;
    float wa0 = sW[c0],     wb0 = sW[128 + c0],     wc0 = sW[256 + c0],     wd0 = sW[384 + c0];
    float wa1 = sW[c0 + 1], wb1 = sW[128 + c0 + 1], wc1 = sW[256 + c0 + 1], wd1 = sW[384 + c0 + 1];
    float bb0 = sb[c0], bb1 = sb[c0 + 1];
    float pp0 = sp[c0], pp1 = sp[c0 + 1];
    #pragma unroll 4
    for (int ii = 0; ii < 64; ++ii) {
        int i = wv * 64 + ii;
        float4 a = *(const float4*)(sxa + i * 4);
        float o0 = fmaxf(a.x * wa0 + a.y * wb0 + a.z * wc0 + a.w * wd0 + bb0, 0.f);
        float o1 = fmaxf(a.x * wa1 + a.y * wb1 + a.z * wc1 + a.w * wd1 + bb1, 0.f);
        ((float2*)(out + (size_t)(nbase + i) * H_))[lane] = make_float2(o0, o1);
        float dt = o0 * pp0 + o1 * pp1;
        for (int mm = 32; mm > 0; mm >>= 1) dt += __shfl_xor(dt, mm);
        if (lane == 0) sdt[i] = dt;
    }
    __syncthreads();
    score[nbase + tid] = tanhf(sdt[tid] * invn[0]);
}

// ---------- levels 1-2 gather-aggregate (f32, int2 edges): 2 edges/wave-iter ----------
__global__ __launch_bounds__(256) void agg_k(const float* __restrict__ Hf,
                                             const int* __restrict__ rowoff,
                                             const int2* __restrict__ esrc,
                                             const float* __restrict__ dis,
                                             const float* __restrict__ bias,
                                             const float* __restrict__ p,
                                             const float* __restrict__ invn,
                                             float* __restrict__ out,
                                             float* __restrict__ score,
                                             int npg, int Gb)
{
    int pb = blockIdx.x;
    int x8 = pb & 7;
    int m  = pb >> 3;
    int g  = x8 + 8 * (m / Gb);
    int lb = m % Gb;
    int j  = lb * 4 + (threadIdx.x >> 6);
    if (j >= npg) return;
    int n = g * npg + j;
    int lane = threadIdx.x & 63;
    int half = lane >> 5;
    int l4 = (lane & 31) * 4;
    float dn = dis[n];
    int beg = rowoff[n], end = rowoff[n + 1];
    float4 acc = make_float4(0.f, 0.f, 0.f, 0.f);
    for (int e = beg + half; e < end; e += 2) {
        int2 ed = esrc[e];
        float c = __int_as_float(ed.y) * dn;
        float4 v = *(const float4*)(Hf + (size_t)ed.x * H_ + l4);
        acc.x += v.x * c; acc.y += v.y * c; acc.z += v.z * c; acc.w += v.w * c;
    }
    acc.x += __shfl_xor(acc.x, 32);
    acc.y += __shfl_xor(acc.y, 32);
    acc.z += __shfl_xor(acc.z, 32);
    acc.w += __shfl_xor(acc.w, 32);
    if (half == 0) {
        float4 hv = *(const float4*)(Hf + (size_t)n * H_ + l4);
        float4 bv = *(const float4*)(bias + l4);
        float s2 = dn * dn;
        float o0 = fmaxf(acc.x + hv.x * s2 + bv.x, 0.f);
        float o1 = fmaxf(acc.y + hv.y * s2 + bv.y, 0.f);
        float o2 = fmaxf(acc.z + hv.z * s2 + bv.z, 0.f);
        float o3 = fmaxf(acc.w + hv.w * s2 + bv.w, 0.f);
        *(float4*)(out + (size_t)n * H_ + l4) = make_float4(o0, o1, o2, o3);
        float4 pv = *(const float4*)(p + l4);
        float dt = o0 * pv.x + o1 * pv.y + o2 * pv.z + o3 * pv.w;
        for (int mm = 16; mm > 0; mm >>= 1) dt += __shfl_xor(dt, mm);
        if ((lane & 31) == 0) score[n] = tanhf(dt * invn[0]);
    }
}

// ---------- radix-select top-k; writes newpos=-1 for unselected ----------
__global__ __launch_bounds__(1024) void radix_topk_k(const float* __restrict__ score,
                                                     int n, int k,
                                                     int* __restrict__ selOld,
                                                     int* __restrict__ newpos)
{
    __shared__ unsigned long long key[2048];
    __shared__ int hist[256];
    __shared__ int sufs[256];
    __shared__ unsigned long long sh_prefix;
    __shared__ int sh_r, sh_done, sh_v, sh_rbin;
    __shared__ int cnt;
    int b = blockIdx.x;
    int t = threadIdx.x;
    const float* s = score + (size_t)b * n;
    #pragma unroll
    for (int h = 0; h < 2; ++h) {
        int i = t + h * 1024;
        unsigned long long pk = 0ull;
        if (i < n) {
            unsigned u = __float_as_uint(s[i]);
            u = (u & 0x80000000u) ? ~u : (u | 0x80000000u);
            pk = ((unsigned long long)u << 32) | (unsigned)(65535 - i);
        }
        key[i] = pk;
    }
    if (t == 0) { sh_prefix = 0ull; sh_r = k; sh_done = 0; cnt = 0; }
    __syncthreads();

    for (int lvl = 0; lvl < 8; ++lvl) {
        if (sh_done) break;
        int bs = 56 - 8 * lvl;
        if (t < 256) hist[t] = 0;
        __syncthreads();
        unsigned long long pref = sh_prefix;
        #pragma unroll
        for (int h = 0; h < 2; ++h) {
            int i = t + h * 1024;
            unsigned long long kk = key[i];
            if (kk != 0ull) {
                bool match = (lvl == 0) || ((kk >> (bs + 8)) == (pref >> (bs + 8)));
                if (match) atomicAdd(&hist[(int)((kk >> bs) & 255)], 1);
            }
        }
        __syncthreads();
        if (t < 256) sufs[t] = hist[t];
        __syncthreads();
        for (int d = 1; d < 256; d <<= 1) {
            int add = (t < 256 && t + d < 256) ? sufs[t + d] : 0;
            __syncthreads();
            if (t < 256) sufs[t] += add;
            __syncthreads();
        }
        if (t < 256) {
            int above = (t == 255) ? 0 : sufs[t + 1];
            if (sufs[t] >= sh_r && above < sh_r) {
                sh_v = t;
                sh_rbin = sh_r - above;
            }
        }
        __syncthreads();
        if (t == 0) {
            int v = sh_v;
            sh_prefix |= ((unsigned long long)v) << bs;
            sh_r = sh_rbin;
            if (hist[v] == sh_rbin) sh_done = 1;
        }
        __syncthreads();
    }
    unsigned long long thr = sh_prefix;
    #pragma unroll
    for (int h = 0; h < 2; ++h) {
        int i = t + h * 1024;
        if (i < n) {
            if (key[i] >= thr) {
                int pos = atomicAdd(&cnt, 1);
                int oldg = b * n + i;
                selOld[b * k + pos] = oldg;
                newpos[oldg] = b * k + pos;
            } else {
                newpos[b * n + i] = -1;
            }
        }
    }
}

// ---------- readout stage 1 (level 3 only) ----------
__global__ __launch_bounds__(512) void readout_part_k(const float* __restrict__ X,
                                                      const int* __restrict__ selOld,
                                                      const float* __restrict__ score,
                                                      int kRows, float* __restrict__ part)
{
    __shared__ float smax[16][128];
    __shared__ float ssum[16][128];
    int b = blockIdx.x / RS;
    int s = blockIdx.x % RS;
    int chunk = (kRows + RS - 1) / RS;
    int j0 = s * chunk;
    int j1 = min(kRows, j0 + chunk);
    int tid = threadIdx.x;
    int f4 = (tid & 31) * 4;
    int q = tid >> 5;
    float4 mx = make_float4(-3.4e38f, -3.4e38f, -3.4e38f, -3.4e38f);
    float4 sm = make_float4(0.f, 0.f, 0.f, 0.f);
    for (int j = j0 + q; j < j1; j += 16) {
        int g = selOld[b * kRows + j];
        float sc = score[g];
        float4 v = *(const float4*)(X + (size_t)g * H_ + f4);
        v.x *= sc; v.y *= sc; v.z *= sc; v.w *= sc;
        mx.x = fmaxf(mx.x, v.x); mx.y = fmaxf(mx.y, v.y);
        mx.z = fmaxf(mx.z, v.z); mx.w = fmaxf(mx.w, v.w);
        sm.x += v.x; sm.y += v.y; sm.z += v.z; sm.w += v.w;
    }
    *(float4*)&smax[q][f4] = mx;
    *(float4*)&ssum[q][f4] = sm;
    __syncthreads();
    if (tid < 128) {
        float m = smax[0][tid], a = ssum[0][tid];
        #pragma unroll
        for (int gq = 1; gq < 16; ++gq) {
            m = fmaxf(m, smax[gq][tid]);
            a += ssum[gq][tid];
        }
        float* pr = part + ((size_t)b * RS + s) * 256;
        pr[tid] = m;
        pr[128 + tid] = a;
    }
}

// ---------- fused readout-fold (variable counts) + 3-layer MLP head ----------
__global__ __launch_bounds__(256) void head_k(const float* __restrict__ part1, int c1,
                                              const float* __restrict__ part2, int c2,
                                              const float* __restrict__ part3, int c3,
                                              const float* __restrict__ lw1, const float* __restrict__ lb1,
                                              const float* __restrict__ lw2, const float* __restrict__ lb2,
                                              const float* __restrict__ lw3, const float* __restrict__ lb3,
                                              float* __restrict__ out)
{
    __shared__ float sZ[256];
    __shared__ float sZ1[128];
    __shared__ float sZ2[64];
    __shared__ float red[256];
    int b = blockIdx.x;
    int t = threadIdx.x;
    {
        int f = t & 127;
        const float* pr1 = part1 + (size_t)b * c1 * 256;
        const float* pr2 = part2 + (size_t)b * c2 * 256;
        const float* pr3 = part3 + (size_t)b * c3 * 256;
        float zv;
        if (t < 128) {
            float m1 = -3.4e38f, m2 = -3.4e38f, m3 = -3.4e38f;
            for (int s = 0; s < c1; ++s) m1 = fmaxf(m1, pr1[s * 256 + f]);
            for (int s = 0; s < c2; ++s) m2 = fmaxf(m2, pr2[s * 256 + f]);
            for (int s = 0; s < c3; ++s) m3 = fmaxf(m3, pr3[s * 256 + f]);
            zv = m1 + m2 + m3;
        } else {
            float s1 = 0.f, s2 = 0.f, s3 = 0.f;
            for (int s = 0; s < c1; ++s) s1 += pr1[s * 256 + 128 + f];
            for (int s = 0; s < c2; ++s) s2 += pr2[s * 256 + 128 + f];
            for (int s = 0; s < c3; ++s) s3 += pr3[s * 256 + 128 + f];
            zv = s1 * (1.0f / (float)K1) + s2 * (1.0f / (float)K2) + s3 * (1.0f / (float)K3);
        }
        sZ[t] = zv;
    }
    __syncthreads();
    {
        int c = t & 127, h = t >> 7;
        float acc = 0.f;
        #pragma unroll
        for (int i = 0; i < 128; ++i) {
            int ii = h * 128 + i;
            acc += sZ[ii] * lw1[ii * 128 + c];
        }
        red[t] = acc;
        __syncthreads();
        if (t < 128) sZ1[t] = fmaxf(red[t] + red[128 + t] + lb1[t], 0.f);
        __syncthreads();
    }
    {
        int c = t & 63, q = t >> 6;
        float acc = 0.f;
        #pragma unroll
        for (int i = 0; i < 32; ++i) {
            int ii = q * 32 + i;
            acc += sZ1[ii] * lw2[ii * 64 + c];
        }
        red[t] = acc;
        __syncthreads();
        if (t < 64) sZ2[t] = fmaxf(red[t] + red[64 + t] + red[128 + t] + red[192 + t] + lb2[t], 0.f);
        __syncthreads();
    }
    {
        if (t < 2 * ACT) {
            int c = t >> 1, h = t & 1;
            float acc = 0.f;
            #pragma unroll
            for (int i = 0; i < 32; ++i) {
                int ii = h * 32 + i;
                acc += sZ2[ii] * lw3[ii * ACT + c];
            }
            red[t] = acc;
        }
        __syncthreads();
        if (t < ACT) {
            float s = red[2 * t] + red[2 * t + 1] + lb3[t];
            out[b * ACT + t] = 1.f / (1.f + expf(-s));
        }
    }
}

extern "C" void kernel_launch(void* const* d_in, const int* in_sizes, int n_in,
                              void* d_out, int out_size, void* d_ws, size_t ws_size,
                              hipStream_t stream)
{
    const float* x   = (const float*)d_in[0];
    const int*   src = (const int*)d_in[1];
    const int*   dst = (const int*)d_in[2];
    const float* W1  = (const float*)d_in[3];
    const float* b1  = (const float*)d_in[4];
    const float* W2  = (const float*)d_in[5];
    const float* b2  = (const float*)d_in[6];
    const float* W3  = (const float*)d_in[7];
    const float* b3  = (const float*)d_in[8];
    const float* p1  = (const float*)d_in[9];
    const float* p2  = (const float*)d_in[10];
    const float* p3  = (const float*)d_in[11];
    const float* lw1 = (const float*)d_in[12];
    const float* lb1 = (const float*)d_in[13];
    const float* lw2 = (const float*)d_in[14];
    const float* lb2 = (const float*)d_in[15];
    const float* lw3 = (const float*)d_in[16];
    const float* lb3 = (const float*)d_in[17];

    char* w = (char*)d_ws;
    size_t off = 0;
    auto alloc = [&](size_t bytes) -> void* {
        void* p = w + off;
        off = (off + bytes + 255) & ~(size_t)255;
        return p;
    };
    float* fA     = (float*)alloc((size_t)N0 * H_ * 4);   // staged h (levels 1-2)
    float* fB     = (float*)alloc((size_t)N0 * H_ * 4);   // gcn output activations
    float* score  = (float*)alloc((size_t)N0 * 4);
    int*   newpos = (int*)  alloc((size_t)N0 * 4);
    int*   deg    = (int*)  alloc((size_t)(N0 + 1) * 4);
    int*   cur    = (int*)  alloc((size_t)N0 * 4);        // adjacent to deg: one memset (L0)
    float* dis    = (float*)alloc((size_t)(N0 + 1) * 4);
    int*   selOld = (int*)  alloc((size_t)N1 * 4);
    int*   ro0    = (int*)  alloc((size_t)(N0 + 1) * 4);
    int*   ro1    = (int*)  alloc((size_t)(N1 + 1) * 4);
    int*   ro2    = (int*)  alloc((size_t)(N2 + 1) * 4);
    int*   bsum   = (int*)  alloc((size_t)1024 * 4);
    int2*  cs0    = (int2*) alloc((size_t)E0 * 8);
    int2*  cs1    = (int2*) alloc((size_t)E0 * 8);
    int2*  cs2    = (int2*) alloc((size_t)E0 * 8);
    float* part1  = (float*)alloc((size_t)B_ * Gm1 * 256 * 4);
    float* part2  = (float*)alloc((size_t)B_ * Gm2 * 256 * 4);
    float* part3  = (float*)alloc((size_t)B_ * RS * 256 * 4);
    unsigned short* WT2 = (unsigned short*)alloc((size_t)128 * 128 * 2);
    unsigned short* WT3 = (unsigned short*)alloc((size_t)128 * 128 * 2);
    float* invn   = (float*)alloc(256);

    const size_t degcur_bytes = (size_t)((char*)cur - (char*)deg) + (size_t)N0 * 4;

    const int GbX  = NPG / 256;          // 8 blocks/graph for aggx
    const int Gb1  = (K1 + 3) / 4;       // 410 (agg level 1)
    const int Gb2  = (K2 + 3) / 4;       // 328 (agg level 2)

    pack_k<<<128, 256, 0, stream>>>(W2, WT2, W3, WT3);

    // ================= level 0: CSR + fused GCN1 =================
    hipMemsetAsync(deg, 0, degcur_bytes, stream);
    count_deg_k<<<E0 / 256, 256, 0, stream>>>(dst, E0, deg);
    {
        int n = N0 + 1, nb = (n + 1023) / 1024;
        scan1_k<<<nb, 1024, 0, stream>>>(deg, ro0, bsum, n);
        scan2_k<<<1, 256, 0, stream>>>(bsum, nb, p1, invn);
        scan3_k<<<(n + 255) / 256, 256, 0, stream>>>(ro0, bsum, n, deg, dis);
    }
    fill_k<<<E0 / 256, 256, 0, stream>>>(src, dst, E0, ro0, cur, dis, cs0);
    aggx_k<<<B_ * GbX, 256, 0, stream>>>(x, ro0, cs0, dis, W1, b1, p1, invn, fB, score, NPG, GbX);

    // ================= pool 1 + level-1 CSR + GCN2 =================
    radix_topk_k<<<B_, 1024, 0, stream>>>(score, NPG, K1, selOld, newpos);
    mmh_k<<<B_ * Gm1, 256, 0, stream>>>(fB, selOld, score, WT2, fA, part1, K1, Gm1);
    {
        int n = N1 + 1, nb = (n + 1023) / 1024;
        scan1b_k<<<nb, 1024, 0, stream>>>(selOld, ro0, cs0, newpos, deg, ro1, bsum, n);
        scan2_k<<<1, 256, 0, stream>>>(bsum, nb, p2, invn);
        scan3_k<<<(n + 255) / 256, 256, 0, stream>>>(ro1, bsum, n, deg, dis);
    }
    fill_row_k<<<(N1 + 255) / 256, 256, 0, stream>>>(selOld, ro0, cs0, newpos, ro1, dis, cs1, N1);
    agg_k<<<B_ * Gb1, 256, 0, stream>>>(fA, ro1, cs1, dis, b2, p2, invn, fB, score, K1, Gb1);

    // ================= pool 2 + level-2 CSR + GCN3 =================
    radix_topk_k<<<B_, 1024, 0, stream>>>(score, K1, K2, selOld, newpos);
    mmh_k<<<B_ * Gm2, 256, 0, stream>>>(fB, selOld, score, WT3, fA, part2, K2, Gm2);
    {
        int n = N2 + 1, nb = (n + 1023) / 1024;
        scan1b_k<<<nb, 1024, 0, stream>>>(selOld, ro1, cs1, newpos, deg, ro2, bsum, n);
        scan2_k<<<1, 256, 0, stream>>>(bsum, nb, p3, invn);
        scan3_k<<<(n + 255) / 256, 256, 0, stream>>>(ro2, bsum, n, deg, dis);
    }
    fill_row_k<<<(N2 + 255) / 256, 256, 0, stream>>>(selOld, ro1, cs1, newpos, ro2, dis, cs2, N2);
    agg_k<<<B_ * Gb2, 256, 0, stream>>>(fA, ro2, cs2, dis, b3, p3, invn, fB, score, K2, Gb2);

    // ================= pool 3 readout =================
    radix_topk_k<<<B_, 1024, 0, stream>>>(score, K2, K3, selOld, newpos);
    readout_part_k<<<B_ * RS, 512, 0, stream>>>(fB, selOld, score, K3, part3);

    // ================= fused readout-fold + MLP head =================
    head_k<<<B_, 256, 0, stream>>>(part1, Gm1, part2, Gm2, part3, RS,
                                   lw1, lb1, lw2, lb2, lw3, lb3, (float*)d_out);
}

// Round 19
// 329.806 us; speedup vs baseline: 1.0209x; 1.0209x over previous
//
#include <hip/hip_runtime.h>
#include <math.h>

namespace {
constexpr int B_   = 64;
constexpr int NPG  = 2048;
constexpr int N0   = B_ * NPG;      // 131072
constexpr int E0   = N0 * 4;        // 524288
constexpr int H_   = 128;
constexpr int K1   = 1639, K2 = 1312, K3 = 1050;
constexpr int N1   = B_ * K1;       // 104896
constexpr int N2   = B_ * K2;       // 83968
constexpr int N3   = B_ * K3;       // 67200
constexpr int ACT  = 124;
constexpr int RS   = 32;            // readout segments (level 3)
constexpr int Gm1  = (K1 + 63) / 64;   // 26 mmh blocks/graph, level 1
constexpr int Gm2  = (K2 + 63) / 64;   // 21 mmh blocks/graph, level 2
}

typedef short bf16x8 __attribute__((ext_vector_type(8)));
typedef float f32x4  __attribute__((ext_vector_type(4)));

__device__ __forceinline__ unsigned short f2bf(float f)
{
    unsigned x = __float_as_uint(f);
    x = x + 0x7FFFu + ((x >> 16) & 1u);    // round-to-nearest-even
    return (unsigned short)(x >> 16);
}

// ---------- pack W2+W3 (128x128 f32 [k][n]) -> WT2,WT3 bf16 [n][k] ----------
__global__ void pack_k(const float* __restrict__ W2, unsigned short* __restrict__ WT2,
                       const float* __restrict__ W3, unsigned short* __restrict__ WT3)
{
    int t = blockIdx.x * 256 + threadIdx.x;   // 32768 threads
    int which = t >> 14;
    int i = t & 16383;
    int n = i >> 7, k = i & 127;
    if (which == 0) WT2[n * 128 + k] = f2bf(W2[k * 128 + n]);
    else            WT3[n * 128 + k] = f2bf(W3[k * 128 + n]);
}

// ---------- h[g,j,:] = (Xin[selOld[g*K+j],:]*score) @ W via bf16 MFMA ----------
// XCD-swizzled per-graph blocks. A staged in LDS bf16 XOR-swizzled; B = WT bf16.
// Readout partials folded IN-WAVE (rr=tid&7 consecutive lanes) via shfl_xor.
__global__ __launch_bounds__(256) void mmh_k(const float* __restrict__ Xin,
                                             const int* __restrict__ selOld,
                                             const float* __restrict__ score,
                                             const unsigned short* __restrict__ WT,
                                             float* __restrict__ C,
                                             float* __restrict__ part,
                                             int K, int Gm)
{
    __shared__ unsigned short sA[64 * 128];   // 16 KB
    char* sAb = (char*)sA;
    int tid = threadIdx.x;
    int pb  = blockIdx.x;
    int x8  = pb & 7;
    int m   = pb >> 3;
    int g   = x8 + 8 * (m / Gm);
    int lb  = m % Gm;
    int jbase = lb * 64;
    const int* selg = selOld + (size_t)g * K;
    int rr = tid & 7;                 // row offset within 8-row stripe (in-wave group)
    int cc = (tid >> 3) * 4;          // this thread's 4 cols

    int   selv[8];
    float scv[8];
    #pragma unroll
    for (int ch = 0; ch < 8; ++ch) {
        int j = jbase + ch * 8 + rr;
        selv[ch] = (j < K) ? selg[j] : -1;
    }
    #pragma unroll
    for (int ch = 0; ch < 8; ++ch)
        scv[ch] = (selv[ch] >= 0) ? score[selv[ch]] : 0.f;

    float4 pmax = make_float4(-3.4e38f, -3.4e38f, -3.4e38f, -3.4e38f);
    float4 psum = make_float4(0.f, 0.f, 0.f, 0.f);
    #pragma unroll
    for (int ch = 0; ch < 8; ++ch) {
        int r = ch * 8 + rr;
        unsigned int lo = 0u, hi = 0u;
        if (selv[ch] >= 0) {
            float sc = scv[ch];
            float4 v = *(const float4*)(Xin + (size_t)selv[ch] * H_ + cc);
            v.x *= sc; v.y *= sc; v.z *= sc; v.w *= sc;
            pmax.x = fmaxf(pmax.x, v.x); pmax.y = fmaxf(pmax.y, v.y);
            pmax.z = fmaxf(pmax.z, v.z); pmax.w = fmaxf(pmax.w, v.w);
            psum.x += v.x; psum.y += v.y; psum.z += v.z; psum.w += v.w;
            unsigned short h0 = f2bf(v.x), h1 = f2bf(v.y);
            unsigned short h2 = f2bf(v.z), h3 = f2bf(v.w);
            lo = (unsigned int)h0 | ((unsigned int)h1 << 16);
            hi = (unsigned int)h2 | ((unsigned int)h3 << 16);
        }
        int off = (r * 256 + cc * 2) ^ ((r & 7) << 4);
        *(unsigned int*)(sAb + off)     = lo;
        *(unsigned int*)(sAb + off + 4) = hi;
    }
    #pragma unroll
    for (int d = 1; d < 8; d <<= 1) {
        pmax.x = fmaxf(pmax.x, __shfl_xor(pmax.x, d));
        pmax.y = fmaxf(pmax.y, __shfl_xor(pmax.y, d));
        pmax.z = fmaxf(pmax.z, __shfl_xor(pmax.z, d));
        pmax.w = fmaxf(pmax.w, __shfl_xor(pmax.w, d));
        psum.x += __shfl_xor(psum.x, d);
        psum.y += __shfl_xor(psum.y, d);
        psum.z += __shfl_xor(psum.z, d);
        psum.w += __shfl_xor(psum.w, d);
    }
    if (rr == 0) {
        float* pr = part + ((size_t)g * Gm + lb) * 256;
        *(float4*)(pr + cc)       = pmax;
        *(float4*)(pr + 128 + cc) = psum;
    }
    __syncthreads();

    int w    = tid >> 6;
    int lane = tid & 63;
    int l16  = lane & 15;
    int lq   = lane >> 4;
    int arow = w * 16 + l16;

    f32x4 acc[8];
    #pragma unroll
    for (int ct = 0; ct < 8; ++ct) acc[ct] = (f32x4){0.f, 0.f, 0.f, 0.f};

    #pragma unroll
    for (int ks = 0; ks < 4; ++ks) {
        int aoff = (arow * 256 + ks * 64 + lq * 16) ^ ((arow & 7) << 4);
        bf16x8 af = *(const bf16x8*)(sAb + aoff);
        #pragma unroll
        for (int ct = 0; ct < 8; ++ct) {
            const unsigned short* bp = WT + (ct * 16 + l16) * 128 + ks * 32 + lq * 8;
            bf16x8 bf = *(const bf16x8*)bp;
            acc[ct] = __builtin_amdgcn_mfma_f32_16x16x32_bf16(af, bf, acc[ct], 0, 0, 0);
        }
    }
    int jb = jbase + w * 16 + lq * 4;
    #pragma unroll
    for (int ct = 0; ct < 8; ++ct) {
        int col = ct * 16 + l16;
        float* cp = C + ((size_t)g * K + jb) * H_ + col;
        if (jb + 0 < K) cp[0 * H_] = acc[ct][0];
        if (jb + 1 < K) cp[1 * H_] = acc[ct][1];
        if (jb + 2 < K) cp[2 * H_] = acc[ct][2];
        if (jb + 3 < K) cp[3 * H_] = acc[ct][3];
    }
}

// ---------- degree count (level 0 only) ----------
__global__ void count_deg_k(const int* __restrict__ dst, int E, int* __restrict__ deg)
{
    int e = blockIdx.x * blockDim.x + threadIdx.x;
    if (e < E) atomicAdd(deg + dst[e], 1);
}

// ---------- exclusive scan over deg[0..n-1] (level 0) ----------
__global__ __launch_bounds__(1024) void scan1_k(const int* __restrict__ in, int* __restrict__ out,
                                                int* __restrict__ bsum, int n)
{
    __shared__ int s[1024];
    int t = threadIdx.x;
    int i = blockIdx.x * 1024 + t;
    int v = (i < n) ? in[i] : 0;
    s[t] = v;
    __syncthreads();
    for (int d = 1; d < 1024; d <<= 1) {
        int add = (t >= d) ? s[t - d] : 0;
        __syncthreads();
        s[t] += add;
        __syncthreads();
    }
    if (i < n) out[i] = s[t] - v;
    if (t == 1023) bsum[blockIdx.x] = s[1023];
}

// ---------- scan with inline degree computation from prev-level CSR ----------
__global__ __launch_bounds__(1024) void scan1b_k(const int* __restrict__ selOld,
                                                 const int* __restrict__ proff,
                                                 const int* __restrict__ pcs,
                                                 const int* __restrict__ newpos,
                                                 int* __restrict__ deg,
                                                 int* __restrict__ out,
                                                 int* __restrict__ bsum, int n)
{
    __shared__ int s[1024];
    int t = threadIdx.x;
    int i = blockIdx.x * 1024 + t;
    int v = 0;
    if (i < n - 1) {
        int o = selOld[i];
        int e1 = proff[o + 1];
        for (int e = proff[o]; e < e1; ++e) v += (newpos[pcs[e]] >= 0) ? 1 : 0;
    }
    if (i < n) deg[i] = v;
    s[t] = v;
    __syncthreads();
    for (int d = 1; d < 1024; d <<= 1) {
        int add = (t >= d) ? s[t - d] : 0;
        __syncthreads();
        s[t] += add;
        __syncthreads();
    }
    if (i < n) out[i] = s[t] - v;
    if (t == 1023) bsum[blockIdx.x] = s[1023];
}

// parallel block-sum scan (nb <= 256) + parallel 1/||p||
__global__ __launch_bounds__(256) void scan2_k(int* __restrict__ bsum, int nb,
                                               const float* __restrict__ p,
                                               float* __restrict__ invnOut)
{
    __shared__ int s[256];
    __shared__ float ps[128];
    int t = threadIdx.x;
    int v = (t < nb) ? bsum[t] : 0;
    s[t] = v;
    if (p && t < 128) ps[t] = p[t] * p[t];
    __syncthreads();
    for (int d = 1; d < 256; d <<= 1) {
        int add = (t >= d) ? s[t - d] : 0;
        __syncthreads();
        s[t] += add;
        __syncthreads();
    }
    if (t < nb) bsum[t] = s[t] - v;
    for (int d = 64; d > 0; d >>= 1) {
        if (p && t < d) ps[t] += ps[t + d];
        __syncthreads();
    }
    if (p && t == 0) *invnOut = rsqrtf(ps[0]);
}

__global__ void scan3_k(int* __restrict__ out, const int* __restrict__ bsum, int n,
                        const int* __restrict__ deg, float* __restrict__ dis)
{
    int i = blockIdx.x * blockDim.x + threadIdx.x;
    if (i < n) {
        out[i] += bsum[i >> 10];
        dis[i] = rsqrtf((float)deg[i] + 1.0f);
    }
}

// ---------- level-0 counting-sort fill (atomic) ----------
__global__ void fill_k(const int* __restrict__ src, const int* __restrict__ dst, int E,
                       const int* __restrict__ rowoff, int* __restrict__ cur,
                       int* __restrict__ esrc)
{
    int e = blockIdx.x * blockDim.x + threadIdx.x;
    if (e >= E) return;
    int d = dst[e];
    int pos = rowoff[d] + atomicAdd(cur + d, 1);
    esrc[pos] = src[e];
}

// ---------- levels 1-2 row-based CSR fill (no atomics) ----------
__global__ void fill_row_k(const int* __restrict__ selOld,
                           const int* __restrict__ proff, const int* __restrict__ pcs,
                           const int* __restrict__ newpos, const int* __restrict__ roff,
                           int* __restrict__ cs, int nNodes)
{
    int i = blockIdx.x * blockDim.x + threadIdx.x;
    if (i >= nNodes) return;
    int o = selOld[i];
    int wptr = roff[i];
    int e1 = proff[o + 1];
    for (int e = proff[o]; e < e1; ++e) {
        int m = newpos[pcs[e]];
        if (m >= 0) cs[wptr++] = m;
    }
}

// ---------- level-0 fused GCN, phase-split ----------
__global__ __launch_bounds__(256) void aggx_k(const float* __restrict__ X,
                                              const int* __restrict__ rowoff,
                                              const int* __restrict__ esrc,
                                              const float* __restrict__ dis,
                                              const float* __restrict__ W1,
                                              const float* __restrict__ b1,
                                              const float* __restrict__ p1,
                                              const float* __restrict__ invn,
                                              float* __restrict__ out,
                                              float* __restrict__ score,
                                              int npg, int Gb)
{
    __shared__ float sW[512];
    __shared__ float sb[128];
    __shared__ float sp[128];
    __shared__ float sxa[256 * 4];
    __shared__ float sdt[256];
    int tid = threadIdx.x;
    for (int i = tid; i < 512; i += 256) sW[i] = W1[i];
    if (tid < 128) { sb[tid] = b1[tid]; sp[tid] = p1[tid]; }
    int pb = blockIdx.x;
    int x8 = pb & 7;
    int m  = pb >> 3;
    int g  = x8 + 8 * (m / Gb);
    int lb = m % Gb;
    int nbase = g * npg + lb * 256;
    int n = nbase + tid;
    float dn = dis[n];
    float4 xa = *(const float4*)(X + (size_t)n * 4);
    float s2 = dn * dn;
    xa.x *= s2; xa.y *= s2; xa.z *= s2; xa.w *= s2;
    int beg = rowoff[n], end = rowoff[n + 1];
    for (int e = beg; e < end; ++e) {
        int s = esrc[e];
        float c = dis[s] * dn;
        float4 xs = *(const float4*)(X + (size_t)s * 4);
        xa.x += xs.x * c; xa.y += xs.y * c; xa.z += xs.z * c; xa.w += xs.w * c;
    }
    *(float4*)(sxa + tid * 4) = xa;
    __syncthreads();
    int wv = tid >> 6;
    int lane = tid & 63;
    int c0 = lane * 2;
    float wa0 = sW[c0],     wb0 = sW[128 + c0],     wc0 = sW[256 + c0],     wd0 = sW[384 + c0];
    float wa1 = sW[c0 + 1], wb1 = sW[128 + c0 + 1], wc1 = sW[256 + c0 + 1], wd1 = sW[384 + c0 + 1];
    float bb0 = sb[c0], bb1 = sb[c0 + 1];
    float pp0 = sp[c0], pp1 = sp[c0 + 1];
    #pragma unroll 4
    for (int ii = 0; ii < 64; ++ii) {
        int i = wv * 64 + ii;
        float4 a = *(const float4*)(sxa + i * 4);
        float o0 = fmaxf(a.x * wa0 + a.y * wb0 + a.z * wc0 + a.w * wd0 + bb0, 0.f);
        float o1 = fmaxf(a.x * wa1 + a.y * wb1 + a.z * wc1 + a.w * wd1 + bb1, 0.f);
        ((float2*)(out + (size_t)(nbase + i) * H_))[lane] = make_float2(o0, o1);
        float dt = o0 * pp0 + o1 * pp1;
        for (int mm = 32; mm > 0; mm >>= 1) dt += __shfl_xor(dt, mm);
        if (lane == 0) sdt[i] = dt;
    }
    __syncthreads();
    score[nbase + tid] = tanhf(sdt[tid] * invn[0]);
}

// ---------- levels 1-2 gather-aggregate (f32): 2 edges/wave-iter, float4 lanes ----------
__global__ __launch_bounds__(256) void agg_k(const float* __restrict__ Hf,
                                             const int* __restrict__ rowoff,
                                             const int* __restrict__ esrc,
                                             const float* __restrict__ dis,
                                             const float* __restrict__ bias,
                                             const float* __restrict__ p,
                                             const float* __restrict__ invn,
                                             float* __restrict__ out,
                                             float* __restrict__ score,
                                             int npg, int Gb)
{
    int pb = blockIdx.x;
    int x8 = pb & 7;
    int m  = pb >> 3;
    int g  = x8 + 8 * (m / Gb);
    int lb = m % Gb;
    int j  = lb * 4 + (threadIdx.x >> 6);
    if (j >= npg) return;
    int n = g * npg + j;
    int lane = threadIdx.x & 63;
    int half = lane >> 5;
    int l4 = (lane & 31) * 4;
    float dn = dis[n];
    int beg = rowoff[n], end = rowoff[n + 1];
    float4 acc = make_float4(0.f, 0.f, 0.f, 0.f);
    for (int e = beg + half; e < end; e += 2) {
        int s = esrc[e];
        float c = dis[s] * dn;
        float4 v = *(const float4*)(Hf + (size_t)s * H_ + l4);
        acc.x += v.x * c; acc.y += v.y * c; acc.z += v.z * c; acc.w += v.w * c;
    }
    acc.x += __shfl_xor(acc.x, 32);
    acc.y += __shfl_xor(acc.y, 32);
    acc.z += __shfl_xor(acc.z, 32);
    acc.w += __shfl_xor(acc.w, 32);
    if (half == 0) {
        float4 hv = *(const float4*)(Hf + (size_t)n * H_ + l4);
        float4 bv = *(const float4*)(bias + l4);
        float s2 = dn * dn;
        float o0 = fmaxf(acc.x + hv.x * s2 + bv.x, 0.f);
        float o1 = fmaxf(acc.y + hv.y * s2 + bv.y, 0.f);
        float o2 = fmaxf(acc.z + hv.z * s2 + bv.z, 0.f);
        float o3 = fmaxf(acc.w + hv.w * s2 + bv.w, 0.f);
        *(float4*)(out + (size_t)n * H_ + l4) = make_float4(o0, o1, o2, o3);
        float4 pv = *(const float4*)(p + l4);
        float dt = o0 * pv.x + o1 * pv.y + o2 * pv.z + o3 * pv.w;
        for (int mm = 16; mm > 0; mm >>= 1) dt += __shfl_xor(dt, mm);
        if ((lane & 31) == 0) score[n] = tanhf(dt * invn[0]);
    }
}

// ---------- radix-select top-k; writes newpos=-1 for unselected ----------
__global__ __launch_bounds__(1024) void radix_topk_k(const float* __restrict__ score,
                                                     int n, int k,
                                                     int* __restrict__ selOld,
                                                     int* __restrict__ newpos)
{
    __shared__ unsigned long long key[2048];
    __shared__ int hist[256];
    __shared__ int sufs[256];
    __shared__ unsigned long long sh_prefix;
    __shared__ int sh_r, sh_done, sh_v, sh_rbin;
    __shared__ int cnt;
    int b = blockIdx.x;
    int t = threadIdx.x;
    const float* s = score + (size_t)b * n;
    #pragma unroll
    for (int h = 0; h < 2; ++h) {
        int i = t + h * 1024;
        unsigned long long pk = 0ull;
        if (i < n) {
            unsigned u = __float_as_uint(s[i]);
            u = (u & 0x80000000u) ? ~u : (u | 0x80000000u);
            pk = ((unsigned long long)u << 32) | (unsigned)(65535 - i);
        }
        key[i] = pk;
    }
    if (t == 0) { sh_prefix = 0ull; sh_r = k; sh_done = 0; cnt = 0; }
    __syncthreads();

    for (int lvl = 0; lvl < 8; ++lvl) {
        if (sh_done) break;
        int bs = 56 - 8 * lvl;
        if (t < 256) hist[t] = 0;
        __syncthreads();
        unsigned long long pref = sh_prefix;
        #pragma unroll
        for (int h = 0; h < 2; ++h) {
            int i = t + h * 1024;
            unsigned long long kk = key[i];
            if (kk != 0ull) {
                bool match = (lvl == 0) || ((kk >> (bs + 8)) == (pref >> (bs + 8)));
                if (match) atomicAdd(&hist[(int)((kk >> bs) & 255)], 1);
            }
        }
        __syncthreads();
        if (t < 256) sufs[t] = hist[t];
        __syncthreads();
        for (int d = 1; d < 256; d <<= 1) {
            int add = (t < 256 && t + d < 256) ? sufs[t + d] : 0;
            __syncthreads();
            if (t < 256) sufs[t] += add;
            __syncthreads();
        }
        if (t < 256) {
            int above = (t == 255) ? 0 : sufs[t + 1];
            if (sufs[t] >= sh_r && above < sh_r) {
                sh_v = t;
                sh_rbin = sh_r - above;
            }
        }
        __syncthreads();
        if (t == 0) {
            int v = sh_v;
            sh_prefix |= ((unsigned long long)v) << bs;
            sh_r = sh_rbin;
            if (hist[v] == sh_rbin) sh_done = 1;
        }
        __syncthreads();
    }
    unsigned long long thr = sh_prefix;
    #pragma unroll
    for (int h = 0; h < 2; ++h) {
        int i = t + h * 1024;
        if (i < n) {
            if (key[i] >= thr) {
                int pos = atomicAdd(&cnt, 1);
                int oldg = b * n + i;
                selOld[b * k + pos] = oldg;
                newpos[oldg] = b * k + pos;
            } else {
                newpos[b * n + i] = -1;
            }
        }
    }
}

// ---------- readout stage 1 (level 3 only) ----------
__global__ __launch_bounds__(512) void readout_part_k(const float* __restrict__ X,
                                                      const int* __restrict__ selOld,
                                                      const float* __restrict__ score,
                                                      int kRows, float* __restrict__ part)
{
    __shared__ float smax[16][128];
    __shared__ float ssum[16][128];
    int b = blockIdx.x / RS;
    int s = blockIdx.x % RS;
    int chunk = (kRows + RS - 1) / RS;
    int j0 = s * chunk;
    int j1 = min(kRows, j0 + chunk);
    int tid = threadIdx.x;
    int f4 = (tid & 31) * 4;
    int q = tid >> 5;
    float4 mx = make_float4(-3.4e38f, -3.4e38f, -3.4e38f, -3.4e38f);
    float4 sm = make_float4(0.f, 0.f, 0.f, 0.f);
    for (int j = j0 + q; j < j1; j += 16) {
        int g = selOld[b * kRows + j];
        float sc = score[g];
        float4 v = *(const float4*)(X + (size_t)g * H_ + f4);
        v.x *= sc; v.y *= sc; v.z *= sc; v.w *= sc;
        mx.x = fmaxf(mx.x, v.x); mx.y = fmaxf(mx.y, v.y);
        mx.z = fmaxf(mx.z, v.z); mx.w = fmaxf(mx.w, v.w);
        sm.x += v.x; sm.y += v.y; sm.z += v.z; sm.w += v.w;
    }
    *(float4*)&smax[q][f4] = mx;
    *(float4*)&ssum[q][f4] = sm;
    __syncthreads();
    if (tid < 128) {
        float m = smax[0][tid], a = ssum[0][tid];
        #pragma unroll
        for (int gq = 1; gq < 16; ++gq) {
            m = fmaxf(m, smax[gq][tid]);
            a += ssum[gq][tid];
        }
        float* pr = part + ((size_t)b * RS + s) * 256;
        pr[tid] = m;
        pr[128 + tid] = a;
    }
}

// ---------- fused readout-fold (variable counts) + 3-layer MLP head ----------
__global__ __launch_bounds__(256) void head_k(const float* __restrict__ part1, int c1,
                                              const float* __restrict__ part2, int c2,
                                              const float* __restrict__ part3, int c3,
                                              const float* __restrict__ lw1, const float* __restrict__ lb1,
                                              const float* __restrict__ lw2, const float* __restrict__ lb2,
                                              const float* __restrict__ lw3, const float* __restrict__ lb3,
                                              float* __restrict__ out)
{
    __shared__ float sZ[256];
    __shared__ float sZ1[128];
    __shared__ float sZ2[64];
    __shared__ float red[256];
    int b = blockIdx.x;
    int t = threadIdx.x;
    {
        int f = t & 127;
        const float* pr1 = part1 + (size_t)b * c1 * 256;
        const float* pr2 = part2 + (size_t)b * c2 * 256;
        const float* pr3 = part3 + (size_t)b * c3 * 256;
        float zv;
        if (t < 128) {
            float m1 = -3.4e38f, m2 = -3.4e38f, m3 = -3.4e38f;
            for (int s = 0; s < c1; ++s) m1 = fmaxf(m1, pr1[s * 256 + f]);
            for (int s = 0; s < c2; ++s) m2 = fmaxf(m2, pr2[s * 256 + f]);
            for (int s = 0; s < c3; ++s) m3 = fmaxf(m3, pr3[s * 256 + f]);
            zv = m1 + m2 + m3;
        } else {
            float s1 = 0.f, s2 = 0.f, s3 = 0.f;
            for (int s = 0; s < c1; ++s) s1 += pr1[s * 256 + 128 + f];
            for (int s = 0; s < c2; ++s) s2 += pr2[s * 256 + 128 + f];
            for (int s = 0; s < c3; ++s) s3 += pr3[s * 256 + 128 + f];
            zv = s1 * (1.0f / (float)K1) + s2 * (1.0f / (float)K2) + s3 * (1.0f / (float)K3);
        }
        sZ[t] = zv;
    }
    __syncthreads();
    {
        int c = t & 127, h = t >> 7;
        float acc = 0.f;
        #pragma unroll
        for (int i = 0; i < 128; ++i) {
            int ii = h * 128 + i;
            acc += sZ[ii] * lw1[ii * 128 + c];
        }
        red[t] = acc;
        __syncthreads();
        if (t < 128) sZ1[t] = fmaxf(red[t] + red[128 + t] + lb1[t], 0.f);
        __syncthreads();
    }
    {
        int c = t & 63, q = t >> 6;
        float acc = 0.f;
        #pragma unroll
        for (int i = 0; i < 32; ++i) {
            int ii = q * 32 + i;
            acc += sZ1[ii] * lw2[ii * 64 + c];
        }
        red[t] = acc;
        __syncthreads();
        if (t < 64) sZ2[t] = fmaxf(red[t] + red[64 + t] + red[128 + t] + red[192 + t] + lb2[t], 0.f);
        __syncthreads();
    }
    {
        if (t < 2 * ACT) {
            int c = t >> 1, h = t & 1;
            float acc = 0.f;
            #pragma unroll
            for (int i = 0; i < 32; ++i) {
                int ii = h * 32 + i;
                acc += sZ2[ii] * lw3[ii * ACT + c];
            }
            red[t] = acc;
        }
        __syncthreads();
        if (t < ACT) {
            float s = red[2 * t] + red[2 * t + 1] + lb3[t];
            out[b * ACT + t] = 1.f / (1.f + expf(-s));
        }
    }
}

extern "C" void kernel_launch(void* const* d_in, const int* in_sizes, int n_in,
                              void* d_out, int out_size, void* d_ws, size_t ws_size,
                              hipStream_t stream)
{
    const float* x   = (const float*)d_in[0];
    const int*   src = (const int*)d_in[1];
    const int*   dst = (const int*)d_in[2];
    const float* W1  = (const float*)d_in[3];
    const float* b1  = (const float*)d_in[4];
    const float* W2  = (const float*)d_in[5];
    const float* b2  = (const float*)d_in[6];
    const float* W3  = (const float*)d_in[7];
    const float* b3  = (const float*)d_in[8];
    const float* p1  = (const float*)d_in[9];
    const float* p2  = (const float*)d_in[10];
    const float* p3  = (const float*)d_in[11];
    const float* lw1 = (const float*)d_in[12];
    const float* lb1 = (const float*)d_in[13];
    const float* lw2 = (const float*)d_in[14];
    const float* lb2 = (const float*)d_in[15];
    const float* lw3 = (const float*)d_in[16];
    const float* lb3 = (const float*)d_in[17];

    char* w = (char*)d_ws;
    size_t off = 0;
    auto alloc = [&](size_t bytes) -> void* {
        void* p = w + off;
        off = (off + bytes + 255) & ~(size_t)255;
        return p;
    };
    float* fA     = (float*)alloc((size_t)N0 * H_ * 4);   // staged h (levels 1-2)
    float* fB     = (float*)alloc((size_t)N0 * H_ * 4);   // gcn output activations
    float* score  = (float*)alloc((size_t)N0 * 4);
    int*   newpos = (int*)  alloc((size_t)N0 * 4);
    int*   deg    = (int*)  alloc((size_t)(N0 + 1) * 4);
    int*   cur    = (int*)  alloc((size_t)N0 * 4);        // adjacent to deg: one memset (L0)
    float* dis    = (float*)alloc((size_t)(N0 + 1) * 4);
    int*   selOld = (int*)  alloc((size_t)N1 * 4);
    int*   ro0    = (int*)  alloc((size_t)(N0 + 1) * 4);
    int*   ro1    = (int*)  alloc((size_t)(N1 + 1) * 4);
    int*   ro2    = (int*)  alloc((size_t)(N2 + 1) * 4);
    int*   bsum   = (int*)  alloc((size_t)1024 * 4);
    int*   cs0    = (int*)  alloc((size_t)E0 * 4);
    int*   cs1    = (int*)  alloc((size_t)E0 * 4);
    int*   cs2    = (int*)  alloc((size_t)E0 * 4);
    float* part1  = (float*)alloc((size_t)B_ * Gm1 * 256 * 4);
    float* part2  = (float*)alloc((size_t)B_ * Gm2 * 256 * 4);
    float* part3  = (float*)alloc((size_t)B_ * RS * 256 * 4);
    unsigned short* WT2 = (unsigned short*)alloc((size_t)128 * 128 * 2);
    unsigned short* WT3 = (unsigned short*)alloc((size_t)128 * 128 * 2);
    float* invn   = (float*)alloc(256);

    const size_t degcur_bytes = (size_t)((char*)cur - (char*)deg) + (size_t)N0 * 4;

    const int GbX  = NPG / 256;          // 8 blocks/graph for aggx
    const int Gb1  = (K1 + 3) / 4;       // 410 (agg level 1)
    const int Gb2  = (K2 + 3) / 4;       // 328 (agg level 2)

    pack_k<<<128, 256, 0, stream>>>(W2, WT2, W3, WT3);

    // ================= level 0: CSR + fused GCN1 =================
    hipMemsetAsync(deg, 0, degcur_bytes, stream);
    count_deg_k<<<E0 / 256, 256, 0, stream>>>(dst, E0, deg);
    {
        int n = N0 + 1, nb = (n + 1023) / 1024;
        scan1_k<<<nb, 1024, 0, stream>>>(deg, ro0, bsum, n);
        scan2_k<<<1, 256, 0, stream>>>(bsum, nb, p1, invn);
        scan3_k<<<(n + 255) / 256, 256, 0, stream>>>(ro0, bsum, n, deg, dis);
    }
    fill_k<<<E0 / 256, 256, 0, stream>>>(src, dst, E0, ro0, cur, cs0);
    aggx_k<<<B_ * GbX, 256, 0, stream>>>(x, ro0, cs0, dis, W1, b1, p1, invn, fB, score, NPG, GbX);

    // ================= pool 1 + level-1 CSR + GCN2 =================
    radix_topk_k<<<B_, 1024, 0, stream>>>(score, NPG, K1, selOld, newpos);
    mmh_k<<<B_ * Gm1, 256, 0, stream>>>(fB, selOld, score, WT2, fA, part1, K1, Gm1);
    {
        int n = N1 + 1, nb = (n + 1023) / 1024;
        scan1b_k<<<nb, 1024, 0, stream>>>(selOld, ro0, cs0, newpos, deg, ro1, bsum, n);
        scan2_k<<<1, 256, 0, stream>>>(bsum, nb, p2, invn);
        scan3_k<<<(n + 255) / 256, 256, 0, stream>>>(ro1, bsum, n, deg, dis);
    }
    fill_row_k<<<(N1 + 255) / 256, 256, 0, stream>>>(selOld, ro0, cs0, newpos, ro1, cs1, N1);
    agg_k<<<B_ * Gb1, 256, 0, stream>>>(fA, ro1, cs1, dis, b2, p2, invn, fB, score, K1, Gb1);

    // ================= pool 2 + level-2 CSR + GCN3 =================
    radix_topk_k<<<B_, 1024, 0, stream>>>(score, K1, K2, selOld, newpos);
    mmh_k<<<B_ * Gm2, 256, 0, stream>>>(fB, selOld, score, WT3, fA, part2, K2, Gm2);
    {
        int n = N2 + 1, nb = (n + 1023) / 1024;
        scan1b_k<<<nb, 1024, 0, stream>>>(selOld, ro1, cs1, newpos, deg, ro2, bsum, n);
        scan2_k<<<1, 256, 0, stream>>>(bsum, nb, p3, invn);
        scan3_k<<<(n + 255) / 256, 256, 0, stream>>>(ro2, bsum, n, deg, dis);
    }
    fill_row_k<<<(N2 + 255) / 256, 256, 0, stream>>>(selOld, ro1, cs1, newpos, ro2, cs2, N2);
    agg_k<<<B_ * Gb2, 256, 0, stream>>>(fA, ro2, cs2, dis, b3, p3, invn, fB, score, K2, Gb2);

    // ================= pool 3 readout =================
    radix_topk_k<<<B_, 1024, 0, stream>>>(score, K2, K3, selOld, newpos);
    readout_part_k<<<B_ * RS, 512, 0, stream>>>(fB, selOld, score, K3, part3);

    // ================= fused readout-fold + MLP head =================
    head_k<<<B_, 256, 0, stream>>>(part1, Gm1, part2, Gm2, part3, RS,
                                   lw1, lb1, lw2, lb2, lw3, lb3, (float*)d_out);
}